// Round 5
// baseline (234.738 us; speedup 1.0000x reference)
//
#include <hip/hip_runtime.h>
#include <math.h>

// MoE router: logits = x @ gate_w  (M=32768, K=2048, N=64 fp32)
// outputs (concat flat, read back as float32):
//   [0 .. 2N)   top_k_weights [N,2]
//   [2N .. 4N)  top_k_indices [N,2] (as float values)
//   [4N]        load_balance_loss scalar
#define N_TOKENS 32768
#define HIDDEN   2048
#define NEXP     64
#define BM 64                  // tokens per block (1 per lane)
#define BK 64                  // k chunk
#define NCHUNK (HIDDEN / BK)   // 32
#define EPW 16                 // experts per thread (wave wv owns experts wv*16..+15)
#define NWAVE 4                // 256 threads
#define NBLK (N_TOKENS / BM)   // 512 blocks
#define XSS 65                 // padded x-tile row stride (transposed stores 2-way free)

__global__ __launch_bounds__(256, 2)
void router_main(const float* __restrict__ x, const float* __restrict__ gw,
                 float* __restrict__ out_w, float* __restrict__ out_i,
                 float* __restrict__ wsP, int* __restrict__ wsC)
{
    __shared__ __align__(16) float xs[2][BK][XSS];   // x tile, column-major-ish [k][tok]
    __shared__ __align__(16) float wt[2][BK][NEXP];  // w tile [k][expert]
    __shared__ float pred[NWAVE][NEXP];
    __shared__ int   cntl[NEXP];
    // logits [64][XSS] aliases xs[0] (exactly fits; xs[0] dead after last chunk)
    float (*logits_s)[XSS] = reinterpret_cast<float(*)[XSS]>(&xs[0][0][0]);

    const int tid  = threadIdx.x;
    const int lane = tid & 63;                                 // token within block
    const int wv   = tid >> 6;                                 // wave id
    const int e0   = __builtin_amdgcn_readfirstlane(wv) * EPW; // expert base (wave-uniform)
    const int m0   = blockIdx.x * BM;
    if (tid < NEXP) cntl[tid] = 0;

    // staging decomposition: thread (f4, tokb); tokens tokb+16r, k-quad f4
    const int f4   = tid & 15;
    const int tokb = tid >> 4;   // 0..15

    float acc[EPW];
    #pragma unroll
    for (int j = 0; j < EPW; ++j) acc[j] = 0.f;

    float4 px[4], pw[4];
    const float4* gw4 = reinterpret_cast<const float4*>(gw);

    // ---- prologue: stage chunk 0 ----
    #pragma unroll
    for (int r = 0; r < 4; ++r)
        px[r] = *reinterpret_cast<const float4*>(
            x + (size_t)(m0 + tokb + 16 * r) * HIDDEN + f4 * 4);
    #pragma unroll
    for (int r = 0; r < 4; ++r) pw[r] = gw4[tid + 256 * r];
    #pragma unroll
    for (int r = 0; r < 4; ++r) {
        const int tok = tokb + 16 * r;
        xs[0][f4 * 4 + 0][tok] = px[r].x;
        xs[0][f4 * 4 + 1][tok] = px[r].y;
        xs[0][f4 * 4 + 2][tok] = px[r].z;
        xs[0][f4 * 4 + 3][tok] = px[r].w;
    }
    {
        float4* wt4 = reinterpret_cast<float4*>(&wt[0][0][0]);
        #pragma unroll
        for (int r = 0; r < 4; ++r) wt4[tid + 256 * r] = pw[r];
    }
    __syncthreads();

    int buf = 0;
    for (int c = 0; c < NCHUNK; ++c) {
        // issue next chunk's global loads early (hide under compute)
        if (c + 1 < NCHUNK) {
            #pragma unroll
            for (int r = 0; r < 4; ++r)
                px[r] = *reinterpret_cast<const float4*>(
                    x + (size_t)(m0 + tokb + 16 * r) * HIDDEN + (c + 1) * BK + f4 * 4);
            #pragma unroll
            for (int r = 0; r < 4; ++r)
                pw[r] = gw4[(c + 1) * (BK * NEXP / 4) + tid + 256 * r];
        }
        // compute: x per-lane b32 (conflict-free), w uniform b128 (broadcast)
        const float* xb = &xs[buf][0][0];
        const float* wb = &wt[buf][0][0];
        #pragma unroll 8
        for (int k = 0; k < BK; ++k) {
            const float xv = xb[k * XSS + lane];
            const float4* wk = reinterpret_cast<const float4*>(wb + k * NEXP + e0);
            const float4 w0 = wk[0];
            const float4 w1 = wk[1];
            const float4 w2 = wk[2];
            const float4 w3 = wk[3];
            acc[ 0] = fmaf(xv, w0.x, acc[ 0]);
            acc[ 1] = fmaf(xv, w0.y, acc[ 1]);
            acc[ 2] = fmaf(xv, w0.z, acc[ 2]);
            acc[ 3] = fmaf(xv, w0.w, acc[ 3]);
            acc[ 4] = fmaf(xv, w1.x, acc[ 4]);
            acc[ 5] = fmaf(xv, w1.y, acc[ 5]);
            acc[ 6] = fmaf(xv, w1.z, acc[ 6]);
            acc[ 7] = fmaf(xv, w1.w, acc[ 7]);
            acc[ 8] = fmaf(xv, w2.x, acc[ 8]);
            acc[ 9] = fmaf(xv, w2.y, acc[ 9]);
            acc[10] = fmaf(xv, w2.z, acc[10]);
            acc[11] = fmaf(xv, w2.w, acc[11]);
            acc[12] = fmaf(xv, w3.x, acc[12]);
            acc[13] = fmaf(xv, w3.y, acc[13]);
            acc[14] = fmaf(xv, w3.z, acc[14]);
            acc[15] = fmaf(xv, w3.w, acc[15]);
        }
        // write next chunk into the other buffer (it was drained by last barrier)
        if (c + 1 < NCHUNK) {
            #pragma unroll
            for (int r = 0; r < 4; ++r) {
                const int tok = tokb + 16 * r;
                xs[buf ^ 1][f4 * 4 + 0][tok] = px[r].x;
                xs[buf ^ 1][f4 * 4 + 1][tok] = px[r].y;
                xs[buf ^ 1][f4 * 4 + 2][tok] = px[r].z;
                xs[buf ^ 1][f4 * 4 + 3][tok] = px[r].w;
            }
            float4* wt4 = reinterpret_cast<float4*>(&wt[buf ^ 1][0][0]);
            #pragma unroll
            for (int r = 0; r < 4; ++r) wt4[tid + 256 * r] = pw[r];
        }
        __syncthreads();
        buf ^= 1;
    }

    // dump logits: thread (wv, lane) owns token=lane, experts e0..e0+15
    #pragma unroll
    for (int j = 0; j < EPW; ++j)
        logits_s[lane][e0 + j] = acc[j];   // bank = lane+e0+j: conflict-free per instr
    __syncthreads();

    // epilogue: wave wv handles tokens wv*16..+15; lane = expert
    const int TPW = BM / NWAVE;   // 16
    float sumP = 0.f;             // per-lane: sum over tokens of prob for expert==lane
    for (int t = 0; t < TPW; ++t) {
        const int m = wv * TPW + t;
        const float l = logits_s[m][lane];
        // top-1 (max value, lowest index on tie — matches jax.lax.top_k)
        float v = l; int idx = lane;
        #pragma unroll
        for (int off = 32; off >= 1; off >>= 1) {
            float ov = __shfl_xor(v, off);
            int   oi = __shfl_xor(idx, off);
            if (ov > v || (ov == v && oi < idx)) { v = ov; idx = oi; }
        }
        const float v1 = v; const int i1 = idx;
        // top-2
        v = (lane == i1) ? -INFINITY : l;
        idx = lane;
        #pragma unroll
        for (int off = 32; off >= 1; off >>= 1) {
            float ov = __shfl_xor(v, off);
            int   oi = __shfl_xor(idx, off);
            if (ov > v || (ov == v && oi < idx)) { v = ov; idx = oi; }
        }
        const float v2 = v; const int i2 = idx;
        // softmax over the two top logits (stable: v2 - v1 <= 0)
        const float ed  = expf(v2 - v1);
        const float wt1 = 1.f / (1.f + ed);
        const float wt2 = ed / (1.f + ed);
        // full softmax over 64 experts (max is v1)
        const float p = expf(l - v1);
        float Z = p;
        #pragma unroll
        for (int off = 32; off >= 1; off >>= 1) Z += __shfl_xor(Z, off);
        sumP += p / Z;
        if (lane == 0) {
            const size_t o = (size_t)(m0 + m) * 2;
            out_w[o]     = wt1;
            out_w[o + 1] = wt2;
            out_i[o]     = (float)i1;
            out_i[o + 1] = (float)i2;
            atomicAdd(&cntl[i1], 1);
            atomicAdd(&cntl[i2], 1);
        }
    }
    pred[wv][lane] = sumP;
    __syncthreads();
    if (tid < NEXP) {
        float s = 0.f;
        #pragma unroll
        for (int w2 = 0; w2 < NWAVE; ++w2) s += pred[w2][tid];
        wsP[(size_t)blockIdx.x * NEXP + tid] = s;
        wsC[(size_t)blockIdx.x * NEXP + tid] = cntl[tid];
    }
}

__global__ void router_finalize(const float* __restrict__ wsP, const int* __restrict__ wsC,
                                float* __restrict__ out_loss)
{
    const int e = threadIdx.x;   // 64 threads, lane = expert
    float P = 0.f, C = 0.f;
    for (int b = 0; b < NBLK; ++b) {
        P += wsP[(size_t)b * NEXP + e];
        C += (float)wsC[(size_t)b * NEXP + e];
    }
    float val = (C / (float)N_TOKENS) * (P / (float)N_TOKENS);
    #pragma unroll
    for (int off = 32; off >= 1; off >>= 1) val += __shfl_xor(val, off);
    if (e == 0) out_loss[0] = (float)NEXP * val;
}

extern "C" void kernel_launch(void* const* d_in, const int* in_sizes, int n_in,
                              void* d_out, int out_size, void* d_ws, size_t ws_size,
                              hipStream_t stream) {
    const float* x  = (const float*)d_in[0];
    const float* gw = (const float*)d_in[1];
    float* out   = (float*)d_out;
    float* out_w = out;                        // [N,2] weights
    float* out_i = out + (size_t)N_TOKENS * 2; // [N,2] indices (as floats)
    float* loss  = out + (size_t)N_TOKENS * 4; // scalar
    float* wsP = (float*)d_ws;                                  // [NBLK][64]
    int*   wsC = (int*)((char*)d_ws + (size_t)NBLK * NEXP * 4); // [NBLK][64]
    hipLaunchKernelGGL(router_main, dim3(NBLK), dim3(256), 0, stream,
                       x, gw, out_w, out_i, wsP, wsC);
    hipLaunchKernelGGL(router_finalize, dim3(1), dim3(64), 0, stream, wsP, wsC, loss);
}

// Round 6
// 201.926 us; speedup vs baseline: 1.1625x; 1.1625x over previous
//
#include <hip/hip_runtime.h>
#include <math.h>

// MoE router: logits = x @ gate_w  (M=32768, K=2048, N=64 fp32)
// outputs (concat flat, read back as float32):
//   [0 .. 2N)   top_k_weights [N,2]
//   [2N .. 4N)  top_k_indices [N,2] (as float values)
//   [4N]        load_balance_loss scalar
#define N_TOKENS 32768
#define HIDDEN   2048
#define NEXP     64
#define BM 64                  // tokens per block
#define KS (HIDDEN / 4)        // 512: K-slice per wave
#define BK 16                  // k per chunk per wave
#define NCHUNK (KS / BK)       // 32
#define NWAVE 4                // 256 threads
#define NBLK (N_TOKENS / BM)   // 512 blocks
#define XS 68                  // padded LDS row stride (floats); 68*4B = 17*16B (b128-aligned)
#define WREG (BK * XS)         // 1088 floats per wave-region per buffer

__global__ __launch_bounds__(256, 2)
void router_main(const float* __restrict__ x, const float* __restrict__ gw,
                 float* __restrict__ out_w, float* __restrict__ out_i,
                 float* __restrict__ wsP, int* __restrict__ wsC)
{
    // arena: xs[2][NWAVE][BK][XS] (34816 B) + ws[2][NWAVE][BK][XS] (34816 B)
    // after the K-loop, aliased as part[NWAVE][BM][65] (66560 B <= 69632 B)
    __shared__ __align__(16) float arena[2 * NWAVE * WREG * 2];   // 17408 floats
    __shared__ float pred[NWAVE][NEXP];
    __shared__ int   cntl[NEXP];

    const int tid  = threadIdx.x;
    const int lane = tid & 63;
    const int rw   = tid >> 6;         // wave id = K-slice id
    const int tg   = lane >> 2;        // token group: tokens tg*4..+3
    const int eg   = lane & 3;         // expert group: experts eg*16..+15
    const int m0   = blockIdx.x * BM;
    if (tid < NEXP) cntl[tid] = 0;

    float* const xs0 = arena;                 // [NWAVE][BK][XS]
    float* const xs1 = arena + NWAVE * WREG;
    float* const ws0 = arena + 2 * NWAVE * WREG;
    float* const ws1 = arena + 3 * NWAVE * WREG;

    // staging decompositions (coalesced global loads)
    const int stok = lane >> 2;        // x: 16 tokens per instr
    const int skq  = lane & 3;         //    4 lanes cover 16 k of one token
    const int kbase = rw * KS;

    float acc[4][16];
    #pragma unroll
    for (int j = 0; j < 4; ++j)
        #pragma unroll
        for (int i = 0; i < 16; ++i) acc[j][i] = 0.f;

    float4 px[4], pw[4];
    const float4* gw4 = reinterpret_cast<const float4*>(gw);

    // ---- prologue: load + store chunk 0 ----
    #pragma unroll
    for (int r = 0; r < 4; ++r)
        px[r] = *reinterpret_cast<const float4*>(
            x + (size_t)(m0 + r * 16 + stok) * HIDDEN + kbase + skq * 4);
    #pragma unroll
    for (int i = 0; i < 4; ++i)
        pw[i] = gw4[(size_t)kbase * 16 + i * 64 + tid % 64 + 0];   // lane-coalesced
    {
        float* xd = xs0 + rw * WREG;
        #pragma unroll
        for (int r = 0; r < 4; ++r) {
            xd[(skq * 4 + 0) * XS + r * 16 + stok] = px[r].x;
            xd[(skq * 4 + 1) * XS + r * 16 + stok] = px[r].y;
            xd[(skq * 4 + 2) * XS + r * 16 + stok] = px[r].z;
            xd[(skq * 4 + 3) * XS + r * 16 + stok] = px[r].w;
        }
        float* wd = ws0 + rw * WREG;
        #pragma unroll
        for (int i = 0; i < 4; ++i) {
            const int kp = i * 4 + (lane >> 4);
            const int e4 = lane & 15;
            *reinterpret_cast<float4*>(wd + kp * XS + e4 * 4) = pw[i];
        }
    }
    __syncthreads();

    const float* xcur = xs0; const float* wcur = ws0;
    float* xnxt = xs1; float* wnxt = ws1;

    for (int c = 0; c < NCHUNK; ++c) {
        // issue next chunk's global loads first (hide latency under compute)
        if (c + 1 < NCHUNK) {
            const int k0 = kbase + (c + 1) * BK;
            #pragma unroll
            for (int r = 0; r < 4; ++r)
                px[r] = *reinterpret_cast<const float4*>(
                    x + (size_t)(m0 + r * 16 + stok) * HIDDEN + k0 + skq * 4);
            #pragma unroll
            for (int i = 0; i < 4; ++i)
                pw[i] = gw4[(size_t)k0 * 16 + i * 64 + lane];
        }
        // compute chunk c: 64 FMA per k, 5 LDS b128 per k (all <=2-way/broadcast)
        {
            const float* xb = xcur + rw * WREG + tg * 4;
            const float* wb = wcur + rw * WREG + eg * 16;
            #pragma unroll 4
            for (int k = 0; k < BK; ++k) {
                const float4 xv = *reinterpret_cast<const float4*>(xb + k * XS);
                const float4 w0 = *reinterpret_cast<const float4*>(wb + k * XS);
                const float4 w1 = *reinterpret_cast<const float4*>(wb + k * XS + 4);
                const float4 w2 = *reinterpret_cast<const float4*>(wb + k * XS + 8);
                const float4 w3 = *reinterpret_cast<const float4*>(wb + k * XS + 12);
                const float xc[4] = {xv.x, xv.y, xv.z, xv.w};
                const float wc[16] = {w0.x, w0.y, w0.z, w0.w, w1.x, w1.y, w1.z, w1.w,
                                      w2.x, w2.y, w2.z, w2.w, w3.x, w3.y, w3.z, w3.w};
                #pragma unroll
                for (int j = 0; j < 4; ++j)
                    #pragma unroll
                    for (int i = 0; i < 16; ++i)
                        acc[j][i] = fmaf(xc[j], wc[i], acc[j][i]);
            }
        }
        // write next chunk into the other buffer
        if (c + 1 < NCHUNK) {
            float* xd = xnxt + rw * WREG;
            #pragma unroll
            for (int r = 0; r < 4; ++r) {
                xd[(skq * 4 + 0) * XS + r * 16 + stok] = px[r].x;
                xd[(skq * 4 + 1) * XS + r * 16 + stok] = px[r].y;
                xd[(skq * 4 + 2) * XS + r * 16 + stok] = px[r].z;
                xd[(skq * 4 + 3) * XS + r * 16 + stok] = px[r].w;
            }
            float* wd = wnxt + rw * WREG;
            #pragma unroll
            for (int i = 0; i < 4; ++i) {
                const int kp = i * 4 + (lane >> 4);
                const int e4 = lane & 15;
                *reinterpret_cast<float4*>(wd + kp * XS + e4 * 4) = pw[i];
            }
        }
        __syncthreads();
        // swap buffers
        const float* tx = xcur; xcur = (const float*)xnxt; xnxt = (float*)tx;
        const float* tw = wcur; wcur = (const float*)wnxt; wnxt = (float*)tw;
    }

    // ---- combine K-split partials via LDS (arena reused as part[NWAVE][BM][65]) ----
    {
        float* part = arena + rw * (BM * 65);
        #pragma unroll
        for (int j = 0; j < 4; ++j)
            #pragma unroll
            for (int i = 0; i < 16; ++i)
                part[(tg * 4 + j) * 65 + eg * 16 + i] = acc[j][i];
    }
    __syncthreads();

    // epilogue: wave rw handles tokens rw*16..+15; lane = expert
    float sumP = 0.f;
    for (int t = 0; t < 16; ++t) {
        const int m = rw * 16 + t;
        float l = 0.f;
        #pragma unroll
        for (int s = 0; s < NWAVE; ++s)
            l += arena[s * (BM * 65) + m * 65 + lane];

        // top-1 (max value, lowest index on tie — matches jax.lax.top_k)
        float v = l; int idx = lane;
        #pragma unroll
        for (int off = 32; off >= 1; off >>= 1) {
            float ov = __shfl_xor(v, off);
            int   oi = __shfl_xor(idx, off);
            if (ov > v || (ov == v && oi < idx)) { v = ov; idx = oi; }
        }
        const float v1 = v; const int i1 = idx;
        // top-2
        v = (lane == i1) ? -INFINITY : l;
        idx = lane;
        #pragma unroll
        for (int off = 32; off >= 1; off >>= 1) {
            float ov = __shfl_xor(v, off);
            int   oi = __shfl_xor(idx, off);
            if (ov > v || (ov == v && oi < idx)) { v = ov; idx = oi; }
        }
        const float v2 = v; const int i2 = idx;
        // softmax over the two top logits (stable: v2 - v1 <= 0)
        const float ed  = expf(v2 - v1);
        const float wt1 = 1.f / (1.f + ed);
        const float wt2 = ed / (1.f + ed);
        // full softmax over 64 experts (max is v1)
        const float p = expf(l - v1);
        float Z = p;
        #pragma unroll
        for (int off = 32; off >= 1; off >>= 1) Z += __shfl_xor(Z, off);
        sumP += p / Z;
        if (lane == 0) {
            const size_t o = (size_t)(m0 + m) * 2;
            out_w[o]     = wt1;
            out_w[o + 1] = wt2;
            out_i[o]     = (float)i1;
            out_i[o + 1] = (float)i2;
            atomicAdd(&cntl[i1], 1);
            atomicAdd(&cntl[i2], 1);
        }
    }
    pred[rw][lane] = sumP;
    __syncthreads();
    if (tid < NEXP) {
        float s = 0.f;
        #pragma unroll
        for (int w2 = 0; w2 < NWAVE; ++w2) s += pred[w2][tid];
        wsP[(size_t)blockIdx.x * NEXP + tid] = s;
        wsC[(size_t)blockIdx.x * NEXP + tid] = cntl[tid];
    }
}

__global__ void router_finalize(const float* __restrict__ wsP, const int* __restrict__ wsC,
                                float* __restrict__ out_loss)
{
    const int e = threadIdx.x;   // 64 threads, lane = expert
    float P = 0.f, C = 0.f;
    for (int b = 0; b < NBLK; ++b) {
        P += wsP[(size_t)b * NEXP + e];
        C += (float)wsC[(size_t)b * NEXP + e];
    }
    float val = (C / (float)N_TOKENS) * (P / (float)N_TOKENS);
    #pragma unroll
    for (int off = 32; off >= 1; off >>= 1) val += __shfl_xor(val, off);
    if (e == 0) out_loss[0] = (float)NEXP * val;
}

extern "C" void kernel_launch(void* const* d_in, const int* in_sizes, int n_in,
                              void* d_out, int out_size, void* d_ws, size_t ws_size,
                              hipStream_t stream) {
    const float* x  = (const float*)d_in[0];
    const float* gw = (const float*)d_in[1];
    float* out   = (float*)d_out;
    float* out_w = out;                        // [N,2] weights
    float* out_i = out + (size_t)N_TOKENS * 2; // [N,2] indices (as floats)
    float* loss  = out + (size_t)N_TOKENS * 4; // scalar
    float* wsP = (float*)d_ws;                                  // [NBLK][64]
    int*   wsC = (int*)((char*)d_ws + (size_t)NBLK * NEXP * 4); // [NBLK][64]
    hipLaunchKernelGGL(router_main, dim3(NBLK), dim3(256), 0, stream,
                       x, gw, out_w, out_i, wsP, wsC);
    hipLaunchKernelGGL(router_finalize, dim3(1), dim3(64), 0, stream, wsP, wsC, loss);
}

// Round 7
// 99.777 us; speedup vs baseline: 2.3526x; 2.0238x over previous
//
#include <hip/hip_runtime.h>
#include <math.h>

// MoE router: logits = x @ gate_w  (M=32768, K=2048, N=64 fp32)
// Split-precision MFMA: x,w -> 2 fp16 limbs each; logits = xh*wh + xh*wl + xl*wh.
// Scaling: x*64, w*256 (denormal safety), descale 2^-14 at epilogue.
// outputs (concat flat, read back as float32):
//   [0 .. 2N)   top_k_weights [N,2]
//   [2N .. 4N)  top_k_indices [N,2] (as float values)
//   [4N]        load_balance_loss scalar
#define N_TOKENS 32768
#define HIDDEN   2048
#define NEXP     64
#define BM 64                   // tokens per block
#define NWAVE 4                 // 256 threads; wave = K-slice
#define NBLK (N_TOKENS / BM)    // 512
#define KSLICE (HIDDEN / NWAVE) // 512
#define KSTEP 32
#define NSTEP (KSLICE / KSTEP)  // 16
#define WV_F 4096               // floats of staging LDS per wave (xtile 2048 + btile 2048)
#define ARENA_F 16640           // >= 4*WV_F and = part[4][64][65]
#define XSCALE 64.f
#define WSCALE 256.f
#define DESCALE (1.f / 16384.f)

typedef __attribute__((ext_vector_type(8))) _Float16 half8;
typedef __attribute__((ext_vector_type(4))) float f32x4;

__device__ __forceinline__ void gload16(const void* g, void* l) {
    __builtin_amdgcn_global_load_lds(
        (const __attribute__((address_space(1))) void*)g,
        (__attribute__((address_space(3))) void*)l, 16, 0, 0);
}

// ---- kernel 0: split gate_w into 2 fp16 limb planes, MFMA-fragment-packed ----
// plane element order: [(S*4 + nt)*64 + lane]*8 + j  <=>  w[32S + (lane>>4)*8 + j][nt*16 + (lane&15)]
__global__ void wsplit_kernel(const float* __restrict__ gw,
                              _Float16* __restrict__ wh, _Float16* __restrict__ wl) {
    const int S   = blockIdx.x;          // 0..63 K-steps
    const int tid = threadIdx.x;         // 256
    const int nt  = tid >> 6;
    const int l   = tid & 63;
    const int col = nt * 16 + (l & 15);
    const int krow = 32 * S + (l >> 4) * 8;
    half8 vh, vl;
    #pragma unroll
    for (int j = 0; j < 8; ++j) {
        const float w = gw[(size_t)(krow + j) * NEXP + col] * WSCALE;
        const _Float16 hh = (_Float16)w;
        vh[j] = hh;
        vl[j] = (_Float16)(w - (float)hh);
    }
    const size_t off = ((size_t)(S * 4 + nt) * 64 + l) * 8;
    *reinterpret_cast<half8*>(wh + off) = vh;
    *reinterpret_cast<half8*>(wl + off) = vl;
}

__global__ __launch_bounds__(256, 2)
void router_main(const float* __restrict__ x,
                 const _Float16* __restrict__ whp, const _Float16* __restrict__ wlp,
                 float* __restrict__ out_w, float* __restrict__ out_i,
                 float* __restrict__ wsP, int* __restrict__ wsC)
{
    // staging arena (per-wave private during K-loop), aliased as part[4][64][65] after
    __shared__ __align__(16) float arena[ARENA_F];
    __shared__ float pred[NWAVE][NEXP];
    __shared__ int   cntl[NEXP];

    const int tid  = threadIdx.x;
    const int lane = tid & 63;
    const int rw   = __builtin_amdgcn_readfirstlane(tid >> 6);   // K-slice id
    const int m0   = blockIdx.x * BM;
    if (tid < NEXP) cntl[tid] = 0;

    float* const xt = arena + rw * WV_F;          // x tile: [64 tok][8 units of 16B], unit-swizzled
    float* const bt = xt + 2048;                  // b tile: [2 limb][4 nt][64 lane][16B]

    // A-stage per-lane constants: instr i covers tokens i*8..i*8+7
    const int stok = lane >> 3;                   // token within 8-row group
    const int su   = (lane & 7) ^ stok;           // swizzled 16B unit (tok&7 == stok)

    f32x4 acc[4][4];
    const f32x4 zero = {0.f, 0.f, 0.f, 0.f};
    #pragma unroll
    for (int mt = 0; mt < 4; ++mt)
        #pragma unroll
        for (int nt = 0; nt < 4; ++nt) acc[mt][nt] = zero;

    for (int s = 0; s < NSTEP; ++s) {
        const int k0 = rw * KSLICE + s * KSTEP;
        // previous step's ds_reads must retire before DMA overwrites the buffer
        asm volatile("s_waitcnt lgkmcnt(0)" ::: "memory");
        // A stage: 8 x 1KB, pre-swizzled global source, linear LDS dest
        #pragma unroll
        for (int i = 0; i < 8; ++i) {
            const float* g = x + (size_t)(m0 + i * 8 + stok) * HIDDEN + k0 + su * 4;
            gload16(g, xt + i * 256);
        }
        // B stage: 2 limb planes x 4KB, already frag-packed (pure linear copy)
        const _Float16* bh = whp + (size_t)(rw * NSTEP + s) * 2048;
        const _Float16* bl = wlp + (size_t)(rw * NSTEP + s) * 2048;
        #pragma unroll
        for (int q = 0; q < 4; ++q) gload16(bh + q * 512 + lane * 8, bt + q * 256);
        #pragma unroll
        for (int q = 0; q < 4; ++q) gload16(bl + q * 512 + lane * 8, bt + 1024 + q * 256);
        asm volatile("s_waitcnt vmcnt(0)" ::: "memory");
        __builtin_amdgcn_sched_barrier(0);

        // B fragments: per-lane 16B, conflict-free
        half8 bfh[4], bfl[4];
        #pragma unroll
        for (int nt = 0; nt < 4; ++nt) {
            bfh[nt] = *reinterpret_cast<const half8*>(bt + nt * 256 + lane * 4);
            bfl[nt] = *reinterpret_cast<const half8*>(bt + 1024 + nt * 256 + lane * 4);
        }
        // A fragments: read fp32 (swizzled units), scale + split into 2 fp16 limbs
        half8 afh[4], afl[4];
        #pragma unroll
        for (int mt = 0; mt < 4; ++mt) {
            const int tok = mt * 16 + (lane & 15);
            const int t7  = lane & 7;              // tok & 7
            const int vb  = (lane >> 4) * 2;
            const float* xrow = xt + tok * 32;
            const f32x4 q0 = *reinterpret_cast<const f32x4*>(xrow + ((vb ^ t7) << 2));
            const f32x4 q1 = *reinterpret_cast<const f32x4*>(xrow + (((vb + 1) ^ t7) << 2));
            half8 ah, al;
            #pragma unroll
            for (int j = 0; j < 4; ++j) {
                const float v = q0[j] * XSCALE;
                const _Float16 hh = (_Float16)v;
                ah[j] = hh; al[j] = (_Float16)(v - (float)hh);
            }
            #pragma unroll
            for (int j = 0; j < 4; ++j) {
                const float v = q1[j] * XSCALE;
                const _Float16 hh = (_Float16)v;
                ah[4 + j] = hh; al[4 + j] = (_Float16)(v - (float)hh);
            }
            afh[mt] = ah; afl[mt] = al;
        }
        // 48 MFMA: hh + hl + lh streams into the same fp32 accumulators
        #pragma unroll
        for (int mt = 0; mt < 4; ++mt)
            #pragma unroll
            for (int nt = 0; nt < 4; ++nt) {
                f32x4 c = acc[mt][nt];
                c = __builtin_amdgcn_mfma_f32_16x16x32_f16(afh[mt], bfh[nt], c, 0, 0, 0);
                c = __builtin_amdgcn_mfma_f32_16x16x32_f16(afh[mt], bfl[nt], c, 0, 0, 0);
                c = __builtin_amdgcn_mfma_f32_16x16x32_f16(afl[mt], bfh[nt], c, 0, 0, 0);
                acc[mt][nt] = c;
            }
    }

    // all waves must be done with staging before the arena is reused as part[]
    __syncthreads();

    // dump K-slice partials: C/D layout col=lane&15, row=(lane>>4)*4+reg (m89-verified)
    {
        float* part = arena + rw * (BM * 65);
        #pragma unroll
        for (int mt = 0; mt < 4; ++mt)
            #pragma unroll
            for (int nt = 0; nt < 4; ++nt)
                #pragma unroll
                for (int r = 0; r < 4; ++r)
                    part[(mt * 16 + (lane >> 4) * 4 + r) * 65 + nt * 16 + (lane & 15)] =
                        acc[mt][nt][r] * DESCALE;
    }
    __syncthreads();

    // epilogue: wave rw handles tokens rw*16..+15; lane = expert  (proven R6 code)
    float sumP = 0.f;
    for (int t = 0; t < 16; ++t) {
        const int m = rw * 16 + t;
        float l = 0.f;
        #pragma unroll
        for (int s2 = 0; s2 < NWAVE; ++s2)
            l += arena[s2 * (BM * 65) + m * 65 + lane];

        // top-1 (max value, lowest index on tie — matches jax.lax.top_k)
        float v = l; int idx = lane;
        #pragma unroll
        for (int off = 32; off >= 1; off >>= 1) {
            float ov = __shfl_xor(v, off);
            int   oi = __shfl_xor(idx, off);
            if (ov > v || (ov == v && oi < idx)) { v = ov; idx = oi; }
        }
        const float v1 = v; const int i1 = idx;
        // top-2
        v = (lane == i1) ? -INFINITY : l;
        idx = lane;
        #pragma unroll
        for (int off = 32; off >= 1; off >>= 1) {
            float ov = __shfl_xor(v, off);
            int   oi = __shfl_xor(idx, off);
            if (ov > v || (ov == v && oi < idx)) { v = ov; idx = oi; }
        }
        const float v2 = v; const int i2 = idx;
        // softmax over the two top logits (stable: v2 - v1 <= 0)
        const float ed  = expf(v2 - v1);
        const float wt1 = 1.f / (1.f + ed);
        const float wt2 = ed / (1.f + ed);
        // full softmax over 64 experts (max is v1)
        const float p = expf(l - v1);
        float Z = p;
        #pragma unroll
        for (int off = 32; off >= 1; off >>= 1) Z += __shfl_xor(Z, off);
        sumP += p / Z;
        if (lane == 0) {
            const size_t o = (size_t)(m0 + m) * 2;
            out_w[o]     = wt1;
            out_w[o + 1] = wt2;
            out_i[o]     = (float)i1;
            out_i[o + 1] = (float)i2;
            atomicAdd(&cntl[i1], 1);
            atomicAdd(&cntl[i2], 1);
        }
    }
    pred[rw][lane] = sumP;
    __syncthreads();
    if (tid < NEXP) {
        float s = 0.f;
        #pragma unroll
        for (int w2 = 0; w2 < NWAVE; ++w2) s += pred[w2][tid];
        wsP[(size_t)blockIdx.x * NEXP + tid] = s;
        wsC[(size_t)blockIdx.x * NEXP + tid] = cntl[tid];
    }
}

__global__ void router_finalize(const float* __restrict__ wsP, const int* __restrict__ wsC,
                                float* __restrict__ out_loss)
{
    const int e = threadIdx.x;   // 64 threads, lane = expert
    float P = 0.f, C = 0.f;
    for (int b = 0; b < NBLK; ++b) {
        P += wsP[(size_t)b * NEXP + e];
        C += (float)wsC[(size_t)b * NEXP + e];
    }
    float val = (C / (float)N_TOKENS) * (P / (float)N_TOKENS);
    #pragma unroll
    for (int off = 32; off >= 1; off >>= 1) val += __shfl_xor(val, off);
    if (e == 0) out_loss[0] = (float)NEXP * val;
}

extern "C" void kernel_launch(void* const* d_in, const int* in_sizes, int n_in,
                              void* d_out, int out_size, void* d_ws, size_t ws_size,
                              hipStream_t stream) {
    const float* x  = (const float*)d_in[0];
    const float* gw = (const float*)d_in[1];
    float* out   = (float*)d_out;
    float* out_w = out;                        // [N,2] weights
    float* out_i = out + (size_t)N_TOKENS * 2; // [N,2] indices (as floats)
    float* loss  = out + (size_t)N_TOKENS * 4; // scalar
    float*    wsP = (float*)d_ws;                                    // 128 KB
    int*      wsC = (int*)((char*)d_ws + 131072);                    // 128 KB
    _Float16* wh  = (_Float16*)((char*)d_ws + 262144);               // 256 KB
    _Float16* wl  = wh + (size_t)HIDDEN * NEXP;                      // 256 KB
    hipLaunchKernelGGL(wsplit_kernel, dim3(HIDDEN / KSTEP), dim3(256), 0, stream, gw, wh, wl);
    hipLaunchKernelGGL(router_main, dim3(NBLK), dim3(256), 0, stream,
                       x, wh, wl, out_w, out_i, wsP, wsC);
    hipLaunchKernelGGL(router_finalize, dim3(1), dim3(64), 0, stream, wsP, wsC, loss);
}